// Round 8
// baseline (755.521 us; speedup 1.0000x reference)
//
#include <hip/hip_runtime.h>
#include <math.h>

#define N_NODES 50000
#define N_EDGES 1600000
#define D 128
#define BN_EPS 1e-5f

#define NSLICE 8
#define SLICE_NODES 6250        // divides 50000 exactly
#define SUBB 24                 // slots per (node, src-slice); Poisson(4), P(>=24)~8e-12
#define ROWL (NSLICE * SUBB)    // 192 u16 per node = 384 B
#define NREP 64                 // BN partial-sum replicas
#define FILL_BLOCKS 2048        // 256 teams/slice, 24-edge chains per thread
#define GEMM_BLOCKS ((N_NODES + 63) / 64)   // 782

typedef __attribute__((ext_vector_type(8))) short short8;
typedef __attribute__((ext_vector_type(8))) unsigned short ushort8v;
typedef __attribute__((ext_vector_type(4))) float f32x4;

// bf16 helpers (manual, RNE)
__device__ __forceinline__ unsigned short f2bf(float f) {
    unsigned u = __float_as_uint(f);
    u += 0x7FFFu + ((u >> 16) & 1u);
    return (unsigned short)(u >> 16);
}
__device__ __forceinline__ float bf2f(unsigned short u) {
    return __uint_as_float(((unsigned)u) << 16);
}

// ============================================================
// Fill body: sub-bucketed u16 CSR, ONE edge pass, XCD-sliced by dst
// (write window 2.4 MB/slice fits private L2). csr[d][t][pos], t=src-slice.
// ============================================================
__device__ __forceinline__ void fill_body(int blk, const int* __restrict__ src,
                                          const int* __restrict__ dst,
                                          unsigned int* __restrict__ cnt8,
                                          unsigned short* __restrict__ csr) {
    int slice = blk & (NSLICE - 1);
    int b = blk >> 3;
    const int nb = FILL_BLOCKS >> 3;
    int lo = slice * SLICE_NODES, hi = lo + SLICE_NODES;
    for (int e = b * 256 + threadIdx.x; e < N_EDGES; e += nb * 256) {
        int d = dst[e];
        if (d >= lo && d < hi) {
            int s = src[e];
            int t = s / SLICE_NODES;
            unsigned pos = atomicAdd(&cnt8[(d << 3) + t], 1u);
            if (pos < SUBB) csr[(size_t)d * ROWL + t * SUBB + pos] = (unsigned short)s;
        }
    }
}

// ============================================================
// GEMM body: outbf[64 rows](bf16) = act(A) @ W  [+ optional dinv row-scale]
//   apply_bn=0: A = Af32 (fp32 -> bf16), act = identity
//   apply_bn=1: A = Abf (bf16), act = relu(a*sc+sh)
// 4 waves x 16 rows; global-direct fragments (m89-verified layouts).
// ============================================================
__device__ __forceinline__ void gemm_body(int bid, const float* __restrict__ Af32,
                                          const unsigned short* __restrict__ Abf,
                                          const unsigned short* __restrict__ Wt,
                                          const float* __restrict__ sc_sh,
                                          const float* __restrict__ dinv,
                                          int apply_bn,
                                          unsigned short* __restrict__ outbf,
                                          unsigned short* Cs) {   // [4][16][136]
    int tid = threadIdx.x;
    int w = tid >> 6;
    int lane = tid & 63;
    int r = lane & 15, quad = lane >> 4;
    int rowbase = bid * 64 + w * 16;
    int arow = rowbase + r;
    int arowc = (arow < N_NODES) ? arow : 0;

    f32x4 acc[8] = {};
#pragma unroll
    for (int kc = 0; kc < 128; kc += 32) {
        int ko = kc + quad * 8;
        short8 a;
        if (apply_bn) {
            short8 araw = *(const short8*)&Abf[(size_t)arowc * D + ko];
            const float* sc = &sc_sh[ko];
            const float* sh = &sc_sh[128 + ko];
#pragma unroll
            for (int j = 0; j < 8; j++) {
                float v = bf2f((unsigned short)araw[j]);
                v = fmaxf(fmaf(v, sc[j], sh[j]), 0.f);
                a[j] = (short)f2bf(v);
            }
        } else {
            float4 v0 = *(const float4*)&Af32[(size_t)arowc * D + ko];
            float4 v1 = *(const float4*)&Af32[(size_t)arowc * D + ko + 4];
            a[0] = (short)f2bf(v0.x); a[1] = (short)f2bf(v0.y);
            a[2] = (short)f2bf(v0.z); a[3] = (short)f2bf(v0.w);
            a[4] = (short)f2bf(v1.x); a[5] = (short)f2bf(v1.y);
            a[6] = (short)f2bf(v1.z); a[7] = (short)f2bf(v1.w);
        }
#pragma unroll
        for (int ct = 0; ct < 8; ct++) {
            short8 b = *(const short8*)&Wt[(size_t)(ct * 16 + r) * D + ko];
            acc[ct] = __builtin_amdgcn_mfma_f32_16x16x32_bf16(a, b, acc[ct], 0, 0, 0);
        }
    }
    float dv[4] = {1.f, 1.f, 1.f, 1.f};
    if (dinv) {
        float4 d4 = *(const float4*)&dinv[rowbase + quad * 4];  // padded past N
        dv[0] = d4.x; dv[1] = d4.y; dv[2] = d4.z; dv[3] = d4.w;
    }
    // epilogue: wave-private LDS staging (no cross-wave deps -> no barrier)
#pragma unroll
    for (int ct = 0; ct < 8; ct++)
#pragma unroll
        for (int i = 0; i < 4; i++)
            Cs[w * 2176 + (quad * 4 + i) * 136 + ct * 16 + r] = f2bf(acc[ct][i] * dv[i]);

    int r2 = lane >> 2;   // 0..15
    int seg = lane & 3;   // 0..3, 32 cols each
    int orow = rowbase + r2;
    if (orow < N_NODES) {
#pragma unroll
        for (int jj = 0; jj < 4; jj++) {
            *(ushort8v*)&outbf[(size_t)orow * D + seg * 32 + jj * 8] =
                *(const ushort8v*)&Cs[w * 2176 + r2 * 136 + seg * 32 + jj * 8];
        }
    }
}

// ============================================================
// Fused: CSR fill (blocks [0,2048)) || layer-0 GEMM (raw, no dinv/BN).
// Independent work; fusion hides gemm0 (~45us) inside fill (~105us).
// ============================================================
__global__ __launch_bounds__(256) void fused_fill_gemm0_kernel(const int* __restrict__ src,
                                                               const int* __restrict__ dst,
                                                               unsigned int* __restrict__ cnt8,
                                                               unsigned short* __restrict__ csr,
                                                               const float* __restrict__ x,
                                                               const unsigned short* __restrict__ Wt0,
                                                               unsigned short* __restrict__ hwB) {
    __shared__ unsigned short Cs[4 * 16 * 136];
    if (blockIdx.x < FILL_BLOCKS) {
        fill_body(blockIdx.x, src, dst, cnt8, csr);
    } else {
        gemm_body(blockIdx.x - FILL_BLOCKS, x, nullptr, Wt0, nullptr, nullptr, 0, hwB, Cs);
    }
}

// standalone GEMM for layers 1,2 (BN fused, dinv pre-scale)
__global__ __launch_bounds__(256) void gemm_mfma_kernel(const unsigned short* __restrict__ Abf,
                                                        const unsigned short* __restrict__ Wt,
                                                        const float* __restrict__ sc_sh,
                                                        const float* __restrict__ dinv,
                                                        unsigned short* __restrict__ outbf) {
    __shared__ unsigned short Cs[4 * 16 * 136];
    gemm_body(blockIdx.x, nullptr, Abf, Wt, sc_sh, dinv, 1, outbf, Cs);
}

__global__ void compute_dinv_kernel(const unsigned int* __restrict__ cnt8, float* __restrict__ dinv) {
    int n = blockIdx.x * blockDim.x + threadIdx.x;
    if (n < N_NODES) {
        const uint4* c = (const uint4*)&cnt8[n << 3];
        uint4 a = c[0], b = c[1];
        unsigned deg = a.x + a.y + a.z + a.w + b.x + b.y + b.z + b.w;
        dinv[n] = rsqrtf((float)deg + 2.0f);   // improved=True: self-loop weight 2
    }
}

// ============================================================
// Per-layer weight prep: Wt[n][k] = bf16(W[k][n]), 3 layers, 3 blocks.
// ============================================================
__global__ void prep_weights_kernel(const float* __restrict__ W0, const float* __restrict__ W1,
                                    const float* __restrict__ W2, unsigned short* __restrict__ Wt) {
    const float* W = (blockIdx.x == 0) ? W0 : (blockIdx.x == 1) ? W1 : W2;
    unsigned short* o = Wt + (size_t)blockIdx.x * D * D;
    int t = threadIdx.x;
    int n = t & 127, half = t >> 7;
    __attribute__((aligned(16))) unsigned short buf[64];
    for (int j = 0; j < 64; j++) {
        int k = half * 64 + j;
        buf[j] = f2bf(W[(size_t)k * D + n]);
    }
    for (int j = 0; j < 64; j += 8)
        *(ushort8v*)&o[(size_t)n * D + half * 64 + j] = *(const ushort8v*)&buf[j];
}

// ============================================================
// Fused gather + BN-stats. Round-6 structure (2 nodes/wave, 32-lane
// groups, ushort4/lane) + explicitly batched inner loop (8 shfls ->
// 8 independent row loads in flight -> fmas).
//   weighted=1 (layer 0): agg[g] = di*( sum dinv[src]*hw[src] + 2*di*hw[g] )
//   weighted=0 (layers 1+, hw pre-scaled): agg[g] = di*( sum hw'[src] + 2*hw'[g] )
// Sub-buckets swept slice 0..7 in phase -> 1.6 MB concurrent window.
// ============================================================
__global__ __launch_bounds__(256) void gather_agg_stats_kernel(const unsigned short* __restrict__ hw,
                                                               const unsigned short* __restrict__ csr,
                                                               const unsigned int* __restrict__ cnt8,
                                                               const float* __restrict__ dinv,
                                                               unsigned short* __restrict__ out,
                                                               float* __restrict__ rep,
                                                               int weighted) {
    __shared__ float part[8][256];
    int grp = threadIdx.x >> 5, lane = threadIdx.x & 31;
    int g = blockIdx.x * 8 + grp;              // 6250 * 8 = 50000 exact
    const ushort4* hwv = (const ushort4*)hw;
    float di = dinv[g];
    ushort4 sv = hwv[(size_t)g * 32 + lane];
    float w0 = weighted ? (2.f * di) : 2.f;
    float4 acc = make_float4(w0 * bf2f(sv.x), w0 * bf2f(sv.y),
                             w0 * bf2f(sv.z), w0 * bf2f(sv.w));
    const unsigned short* row = csr + (size_t)g * ROWL;
#pragma unroll 1
    for (int t = 0; t < NSLICE; t++) {
        int dt = (int)cnt8[(g << 3) + t];
        if (dt > SUBB) dt = SUBB;
        int sidx = 0; float wv = 1.f;
        if (lane < dt) {
            sidx = (int)row[t * SUBB + lane];
            if (weighted) wv = dinv[sidx];
        }
        if (weighted) {
#pragma unroll 1
            for (int j0 = 0; j0 < dt; j0 += 8) {
                int m = dt - j0; if (m > 8) m = 8;
                int sj[8]; float wj[8]; ushort4 v[8];
#pragma unroll
                for (int j = 0; j < 8; j++) {
                    sj[j] = __shfl(sidx, j0 + j, 32);
                    wj[j] = __shfl(wv, j0 + j, 32);
                }
#pragma unroll
                for (int j = 0; j < 8; j++) if (j < m) v[j] = hwv[(size_t)sj[j] * 32 + lane];
#pragma unroll
                for (int j = 0; j < 8; j++) if (j < m) {
                    acc.x = fmaf(wj[j], bf2f(v[j].x), acc.x);
                    acc.y = fmaf(wj[j], bf2f(v[j].y), acc.y);
                    acc.z = fmaf(wj[j], bf2f(v[j].z), acc.z);
                    acc.w = fmaf(wj[j], bf2f(v[j].w), acc.w);
                }
            }
        } else {
#pragma unroll 1
            for (int j0 = 0; j0 < dt; j0 += 8) {
                int m = dt - j0; if (m > 8) m = 8;
                int sj[8]; ushort4 v[8];
#pragma unroll
                for (int j = 0; j < 8; j++) sj[j] = __shfl(sidx, j0 + j, 32);
#pragma unroll
                for (int j = 0; j < 8; j++) if (j < m) v[j] = hwv[(size_t)sj[j] * 32 + lane];
#pragma unroll
                for (int j = 0; j < 8; j++) if (j < m) {
                    acc.x += bf2f(v[j].x); acc.y += bf2f(v[j].y);
                    acc.z += bf2f(v[j].z); acc.w += bf2f(v[j].w);
                }
            }
        }
    }
    acc.x *= di; acc.y *= di; acc.z *= di; acc.w *= di;
    ushort4 o;
    o.x = f2bf(acc.x); o.y = f2bf(acc.y); o.z = f2bf(acc.z); o.w = f2bf(acc.w);
    ((ushort4*)out)[(size_t)g * 32 + lane] = o;

    // BN partials: part[grp][c]=sum, part[grp][128+c]=sumsq (c = lane*4+k)
    ((float4*)part[grp])[lane] = acc;
    float4 sq = make_float4(acc.x * acc.x, acc.y * acc.y, acc.z * acc.z, acc.w * acc.w);
    ((float4*)&part[grp][128])[lane] = sq;
    __syncthreads();
    int c = threadIdx.x;
    float tot = 0.f;
#pragma unroll
    for (int g2 = 0; g2 < 8; g2++) tot += part[g2][c];
    atomicAdd(&rep[(blockIdx.x & (NREP - 1)) * 256 + c], tot);
}

// ============================================================
// Reduce NREP replicas -> sc/sh; re-zero replicas for next layer.
// ============================================================
__global__ void bn_reduce_finalize_kernel(const float* __restrict__ gamma,
                                          const float* __restrict__ beta,
                                          float* __restrict__ rep,
                                          float* __restrict__ sc_sh) {
    int c = threadIdx.x;
    if (c >= 128) return;
    float s = 0.f, q = 0.f;
#pragma unroll 4
    for (int rr = 0; rr < NREP; rr++) {
        s += rep[rr * 256 + c];
        q += rep[rr * 256 + 128 + c];
        rep[rr * 256 + c] = 0.f;
        rep[rr * 256 + 128 + c] = 0.f;
    }
    float inv_n = 1.0f / (float)N_NODES;
    float mean = s * inv_n;
    float var = q * inv_n - mean * mean;
    float inv = rsqrtf(var + BN_EPS);
    float sc = gamma[c] * inv;
    sc_sh[c] = sc;
    sc_sh[128 + c] = beta[c] - mean * sc;
}

// final layer: bf16 agg -> BN+ReLU -> fp32 d_out
__global__ void bn_apply_kernel(const unsigned short* __restrict__ h,
                                const float* __restrict__ sc_sh,
                                float* __restrict__ out) {
    int i = blockIdx.x * blockDim.x + threadIdx.x;
    int stride = gridDim.x * blockDim.x;
    const int total = N_NODES * 32;
    for (; i < total; i += stride) {
        int cg = i & 31;
        ushort4 u = ((const ushort4*)h)[i];
        float4 sc = ((const float4*)sc_sh)[cg];
        float4 sh = ((const float4*)sc_sh)[32 + cg];
        float4 v;
        v.x = fmaxf(fmaf(bf2f(u.x), sc.x, sh.x), 0.f);
        v.y = fmaxf(fmaf(bf2f(u.y), sc.y, sh.y), 0.f);
        v.z = fmaxf(fmaf(bf2f(u.z), sc.z, sh.z), 0.f);
        v.w = fmaxf(fmaf(bf2f(u.w), sc.w, sh.w), 0.f);
        ((float4*)out)[i] = v;
    }
}

// ============================================================
// Launch
// ============================================================
extern "C" void kernel_launch(void* const* d_in, const int* in_sizes, int n_in,
                              void* d_out, int out_size, void* d_ws, size_t ws_size,
                              hipStream_t stream) {
    const float* x = (const float*)d_in[0];
    const int* ei = (const int*)d_in[1];
    const int* src = ei;
    const int* dst = ei + N_EDGES;
    const float* Wm[3] = {(const float*)d_in[2], (const float*)d_in[6], (const float*)d_in[10]};
    const float* gm[3] = {(const float*)d_in[4], (const float*)d_in[8], (const float*)d_in[12]};
    const float* bm[3] = {(const float*)d_in[5], (const float*)d_in[9], (const float*)d_in[13]};

    char* p = (char*)d_ws;
    auto carve = [&](size_t bytes) { char* r = p; p += (bytes + 255) & ~(size_t)255; return r; };
    unsigned short* hwB    = (unsigned short*)carve((size_t)N_NODES * D * sizeof(unsigned short));
    unsigned short* aggbf  = (unsigned short*)carve((size_t)N_NODES * D * sizeof(unsigned short));
    unsigned short* Wt     = (unsigned short*)carve((size_t)3 * D * D * sizeof(unsigned short));
    float*          dinv   = (float*)carve((N_NODES + 64) * sizeof(float));
    unsigned int*   cnt8   = (unsigned int*)carve((size_t)(N_NODES * 8 + NREP * 256) * sizeof(unsigned int));
    float*          rep    = (float*)(cnt8 + (size_t)N_NODES * 8);
    unsigned short* csr    = (unsigned short*)carve((size_t)N_NODES * ROWL * sizeof(unsigned short));
    float*          sc_sh  = (float*)carve(256 * sizeof(float));

    // ---- prep: zero counters+BN replicas, transpose weights ----
    hipMemsetAsync(cnt8, 0, (size_t)(N_NODES * 8 + NREP * 256) * sizeof(unsigned int), stream);
    prep_weights_kernel<<<3, 256, 0, stream>>>(Wm[0], Wm[1], Wm[2], Wt);

    // ---- fused: CSR fill || layer-0 GEMM (independent) ----
    fused_fill_gemm0_kernel<<<FILL_BLOCKS + GEMM_BLOCKS, 256, 0, stream>>>(
        src, dst, cnt8, csr, x, Wt, hwB);
    compute_dinv_kernel<<<(N_NODES + 255) / 256, 256, 0, stream>>>(cnt8, dinv);

    // ---- layer 0: weighted gather (hw unscaled) ----
    gather_agg_stats_kernel<<<N_NODES / 8, 256, 0, stream>>>(hwB, csr, cnt8, dinv, aggbf, rep, 1);
    bn_reduce_finalize_kernel<<<1, 128, 0, stream>>>(gm[0], bm[0], rep, sc_sh);

    // ---- layers 1,2: BN fused into GEMM, dinv pre-scaled hw ----
    for (int l = 1; l < 3; l++) {
        gemm_mfma_kernel<<<GEMM_BLOCKS, 256, 0, stream>>>(aggbf, Wt + (size_t)l * D * D, sc_sh, dinv, hwB);
        gather_agg_stats_kernel<<<N_NODES / 8, 256, 0, stream>>>(hwB, csr, cnt8, dinv, aggbf, rep, 0);
        bn_reduce_finalize_kernel<<<1, 128, 0, stream>>>(gm[l], bm[l], rep, sc_sh);
    }
    bn_apply_kernel<<<2048, 256, 0, stream>>>(aggbf, sc_sh, (float*)d_out);
}

// Round 9
// 586.670 us; speedup vs baseline: 1.2878x; 1.2878x over previous
//
#include <hip/hip_runtime.h>
#include <math.h>

#define N_NODES 50000
#define N_EDGES 1600000
#define D 128
#define BN_EPS 1e-5f

#define NSLICE 8
#define SLICE_NODES 6250        // divides 50000 exactly
#define SUBB 24                 // slots per (node, src-slice); Poisson(4), P(>=24)~8e-12
#define ROWL (NSLICE * SUBB)    // 192 u16 per node = 384 B
#define NREP 64                 // BN partial-sum replicas
#define FILL_BLOCKS 2048        // 256 teams/slice
#define GEMM_BLOCKS ((N_NODES + 63) / 64)   // 782

typedef __attribute__((ext_vector_type(8))) short short8;
typedef __attribute__((ext_vector_type(8))) unsigned short ushort8v;
typedef __attribute__((ext_vector_type(4))) float f32x4;

// bf16 helpers (manual, RNE)
__device__ __forceinline__ unsigned short f2bf(float f) {
    unsigned u = __float_as_uint(f);
    u += 0x7FFFu + ((u >> 16) & 1u);
    return (unsigned short)(u >> 16);
}
__device__ __forceinline__ float bf2f(unsigned short u) {
    return __uint_as_float(((unsigned)u) << 16);
}

// ============================================================
// Fill body: sub-bucketed u16 CSR, ONE edge pass, XCD-sliced by dst
// (write window 2.4 MB/slice fits private L2). csr[d][t][pos], t=src-slice.
// ============================================================
__device__ __forceinline__ void fill_body(int blk, const int* __restrict__ src,
                                          const int* __restrict__ dst,
                                          unsigned int* __restrict__ cnt8,
                                          unsigned short* __restrict__ csr) {
    int slice = blk & (NSLICE - 1);
    int b = blk >> 3;
    const int nb = FILL_BLOCKS >> 3;
    int lo = slice * SLICE_NODES, hi = lo + SLICE_NODES;
    for (int e = b * 256 + threadIdx.x; e < N_EDGES; e += nb * 256) {
        int d = dst[e];
        if (d >= lo && d < hi) {
            int s = src[e];
            int t = s / SLICE_NODES;
            unsigned pos = atomicAdd(&cnt8[(d << 3) + t], 1u);
            if (pos < SUBB) csr[(size_t)d * ROWL + t * SUBB + pos] = (unsigned short)s;
        }
    }
}

// ============================================================
// GEMM body: outbf[64 rows](bf16) = act(A) @ W  [+ optional dinv row-scale]
//   apply_bn=0: A = Af32 (fp32 -> bf16), act = identity
//   apply_bn=1: A = Abf (bf16), act = relu(a*sc+sh)
// 4 waves x 16 rows; global-direct fragments (m89-verified layouts).
// ============================================================
__device__ __forceinline__ void gemm_body(int bid, const float* __restrict__ Af32,
                                          const unsigned short* __restrict__ Abf,
                                          const unsigned short* __restrict__ Wt,
                                          const float* __restrict__ sc_sh,
                                          const float* __restrict__ dinv,
                                          int apply_bn,
                                          unsigned short* __restrict__ outbf,
                                          unsigned short* Cs) {   // [4][16][136]
    int tid = threadIdx.x;
    int w = tid >> 6;
    int lane = tid & 63;
    int r = lane & 15, quad = lane >> 4;
    int rowbase = bid * 64 + w * 16;
    int arow = rowbase + r;
    int arowc = (arow < N_NODES) ? arow : 0;

    f32x4 acc[8] = {};
#pragma unroll
    for (int kc = 0; kc < 128; kc += 32) {
        int ko = kc + quad * 8;
        short8 a;
        if (apply_bn) {
            short8 araw = *(const short8*)&Abf[(size_t)arowc * D + ko];
            const float* sc = &sc_sh[ko];
            const float* sh = &sc_sh[128 + ko];
#pragma unroll
            for (int j = 0; j < 8; j++) {
                float v = bf2f((unsigned short)araw[j]);
                v = fmaxf(fmaf(v, sc[j], sh[j]), 0.f);
                a[j] = (short)f2bf(v);
            }
        } else {
            float4 v0 = *(const float4*)&Af32[(size_t)arowc * D + ko];
            float4 v1 = *(const float4*)&Af32[(size_t)arowc * D + ko + 4];
            a[0] = (short)f2bf(v0.x); a[1] = (short)f2bf(v0.y);
            a[2] = (short)f2bf(v0.z); a[3] = (short)f2bf(v0.w);
            a[4] = (short)f2bf(v1.x); a[5] = (short)f2bf(v1.y);
            a[6] = (short)f2bf(v1.z); a[7] = (short)f2bf(v1.w);
        }
#pragma unroll
        for (int ct = 0; ct < 8; ct++) {
            short8 b = *(const short8*)&Wt[(size_t)(ct * 16 + r) * D + ko];
            acc[ct] = __builtin_amdgcn_mfma_f32_16x16x32_bf16(a, b, acc[ct], 0, 0, 0);
        }
    }
    float dv[4] = {1.f, 1.f, 1.f, 1.f};
    if (dinv) {
        float4 d4 = *(const float4*)&dinv[rowbase + quad * 4];  // padded past N
        dv[0] = d4.x; dv[1] = d4.y; dv[2] = d4.z; dv[3] = d4.w;
    }
    // epilogue: wave-private LDS staging (no cross-wave deps -> no barrier)
#pragma unroll
    for (int ct = 0; ct < 8; ct++)
#pragma unroll
        for (int i = 0; i < 4; i++)
            Cs[w * 2176 + (quad * 4 + i) * 136 + ct * 16 + r] = f2bf(acc[ct][i] * dv[i]);

    int r2 = lane >> 2;   // 0..15
    int seg = lane & 3;   // 0..3, 32 cols each
    int orow = rowbase + r2;
    if (orow < N_NODES) {
#pragma unroll
        for (int jj = 0; jj < 4; jj++) {
            *(ushort8v*)&outbf[(size_t)orow * D + seg * 32 + jj * 8] =
                *(const ushort8v*)&Cs[w * 2176 + r2 * 136 + seg * 32 + jj * 8];
        }
    }
}

// ============================================================
// Fused: CSR fill (blocks [0,2048)) || layer-0 GEMM (raw, no dinv/BN).
// Independent work; fusion hides gemm0 (~45us) inside fill (~105us).
// ============================================================
__global__ __launch_bounds__(256) void fused_fill_gemm0_kernel(const int* __restrict__ src,
                                                               const int* __restrict__ dst,
                                                               unsigned int* __restrict__ cnt8,
                                                               unsigned short* __restrict__ csr,
                                                               const float* __restrict__ x,
                                                               const unsigned short* __restrict__ Wt0,
                                                               unsigned short* __restrict__ hwB) {
    __shared__ unsigned short Cs[4 * 16 * 136];
    if (blockIdx.x < FILL_BLOCKS) {
        fill_body(blockIdx.x, src, dst, cnt8, csr);
    } else {
        gemm_body(blockIdx.x - FILL_BLOCKS, x, nullptr, Wt0, nullptr, nullptr, 0, hwB, Cs);
    }
}

// standalone GEMM for layers 1,2 (BN fused, dinv pre-scale)
__global__ __launch_bounds__(256) void gemm_mfma_kernel(const unsigned short* __restrict__ Abf,
                                                        const unsigned short* __restrict__ Wt,
                                                        const float* __restrict__ sc_sh,
                                                        const float* __restrict__ dinv,
                                                        unsigned short* __restrict__ outbf) {
    __shared__ unsigned short Cs[4 * 16 * 136];
    gemm_body(blockIdx.x, nullptr, Abf, Wt, sc_sh, dinv, 1, outbf, Cs);
}

__global__ void compute_dinv_kernel(const unsigned int* __restrict__ cnt8, float* __restrict__ dinv) {
    int n = blockIdx.x * blockDim.x + threadIdx.x;
    if (n < N_NODES) {
        const uint4* c = (const uint4*)&cnt8[n << 3];
        uint4 a = c[0], b = c[1];
        unsigned deg = a.x + a.y + a.z + a.w + b.x + b.y + b.z + b.w;
        dinv[n] = rsqrtf((float)deg + 2.0f);   // improved=True: self-loop weight 2
    }
}

// ============================================================
// Per-layer weight prep: Wt[n][k] = bf16(W[k][n]), 3 layers, 3 blocks.
// ============================================================
__global__ void prep_weights_kernel(const float* __restrict__ W0, const float* __restrict__ W1,
                                    const float* __restrict__ W2, unsigned short* __restrict__ Wt) {
    const float* W = (blockIdx.x == 0) ? W0 : (blockIdx.x == 1) ? W1 : W2;
    unsigned short* o = Wt + (size_t)blockIdx.x * D * D;
    int t = threadIdx.x;
    int n = t & 127, half = t >> 7;
    __attribute__((aligned(16))) unsigned short buf[64];
    for (int j = 0; j < 64; j++) {
        int k = half * 64 + j;
        buf[j] = f2bf(W[(size_t)k * D + n]);
    }
    for (int j = 0; j < 64; j += 8)
        *(ushort8v*)&o[(size_t)n * D + half * 64 + j] = *(const ushort8v*)&buf[j];
}

// ============================================================
// Fused gather + BN-stats — EXACT round-6 inner structure (simple
// shfl->load->add loop; VGPR~12, occupancy ~0.7-0.8 is what makes it
// fast; manual batching regressed twice: r7 129us, r8 170us).
//   weighted=1 (layer 0, hw raw):   agg = di*( sum dinv[s]*hw[s] + 2*di*hw[g] )
//   weighted=0 (layers 1+, hw pre-scaled): agg = di*( sum hw'[s] + 2*hw'[g] )
// 2 nodes/wave (32-lane groups), ushort4/lane. Sub-buckets swept
// slice 0..7 in phase -> 1.6 MB concurrent hw window per phase.
// ============================================================
__global__ __launch_bounds__(256) void gather_agg_stats_kernel(const unsigned short* __restrict__ hw,
                                                               const unsigned short* __restrict__ csr,
                                                               const unsigned int* __restrict__ cnt8,
                                                               const float* __restrict__ dinv,
                                                               unsigned short* __restrict__ out,
                                                               float* __restrict__ rep,
                                                               int weighted) {
    __shared__ float part[8][256];
    int grp = threadIdx.x >> 5, lane = threadIdx.x & 31;
    int g = blockIdx.x * 8 + grp;              // 6250 * 8 = 50000 exact
    const ushort4* hwv = (const ushort4*)hw;
    float di = dinv[g];
    ushort4 sv = hwv[(size_t)g * 32 + lane];
    float w0 = weighted ? (2.f * di) : 2.f;
    float4 acc = make_float4(w0 * bf2f(sv.x), w0 * bf2f(sv.y),
                             w0 * bf2f(sv.z), w0 * bf2f(sv.w));
    const unsigned short* row = csr + (size_t)g * ROWL;
#pragma unroll 1
    for (int t = 0; t < NSLICE; t++) {
        int dt = (int)cnt8[(g << 3) + t];
        if (dt > SUBB) dt = SUBB;
        int sidx = 0; float wv = 0.f;
        if (lane < dt) {
            sidx = (int)row[t * SUBB + lane];
            if (weighted) wv = dinv[sidx];
        }
        if (weighted) {
            for (int j = 0; j < dt; j++) {
                int sj = __shfl(sidx, j, 32);
                float wj = __shfl(wv, j, 32);
                ushort4 v = hwv[(size_t)sj * 32 + lane];
                acc.x = fmaf(wj, bf2f(v.x), acc.x);
                acc.y = fmaf(wj, bf2f(v.y), acc.y);
                acc.z = fmaf(wj, bf2f(v.z), acc.z);
                acc.w = fmaf(wj, bf2f(v.w), acc.w);
            }
        } else {
            for (int j = 0; j < dt; j++) {
                int sj = __shfl(sidx, j, 32);
                ushort4 v = hwv[(size_t)sj * 32 + lane];
                acc.x += bf2f(v.x); acc.y += bf2f(v.y);
                acc.z += bf2f(v.z); acc.w += bf2f(v.w);
            }
        }
    }
    acc.x *= di; acc.y *= di; acc.z *= di; acc.w *= di;
    ushort4 o;
    o.x = f2bf(acc.x); o.y = f2bf(acc.y); o.z = f2bf(acc.z); o.w = f2bf(acc.w);
    ((ushort4*)out)[(size_t)g * 32 + lane] = o;

    // BN partials: part[grp][c]=sum, part[grp][128+c]=sumsq (c = lane*4+k)
    ((float4*)part[grp])[lane] = acc;
    float4 sq = make_float4(acc.x * acc.x, acc.y * acc.y, acc.z * acc.z, acc.w * acc.w);
    ((float4*)&part[grp][128])[lane] = sq;
    __syncthreads();
    int c = threadIdx.x;
    float tot = 0.f;
#pragma unroll
    for (int g2 = 0; g2 < 8; g2++) tot += part[g2][c];
    atomicAdd(&rep[(blockIdx.x & (NREP - 1)) * 256 + c], tot);
}

// ============================================================
// Reduce NREP replicas -> sc/sh; re-zero replicas for next layer.
// ============================================================
__global__ void bn_reduce_finalize_kernel(const float* __restrict__ gamma,
                                          const float* __restrict__ beta,
                                          float* __restrict__ rep,
                                          float* __restrict__ sc_sh) {
    int c = threadIdx.x;
    if (c >= 128) return;
    float s = 0.f, q = 0.f;
#pragma unroll 4
    for (int rr = 0; rr < NREP; rr++) {
        s += rep[rr * 256 + c];
        q += rep[rr * 256 + 128 + c];
        rep[rr * 256 + c] = 0.f;
        rep[rr * 256 + 128 + c] = 0.f;
    }
    float inv_n = 1.0f / (float)N_NODES;
    float mean = s * inv_n;
    float var = q * inv_n - mean * mean;
    float inv = rsqrtf(var + BN_EPS);
    float sc = gamma[c] * inv;
    sc_sh[c] = sc;
    sc_sh[128 + c] = beta[c] - mean * sc;
}

// final layer: bf16 agg -> BN+ReLU -> fp32 d_out
__global__ void bn_apply_kernel(const unsigned short* __restrict__ h,
                                const float* __restrict__ sc_sh,
                                float* __restrict__ out) {
    int i = blockIdx.x * blockDim.x + threadIdx.x;
    int stride = gridDim.x * blockDim.x;
    const int total = N_NODES * 32;
    for (; i < total; i += stride) {
        int cg = i & 31;
        ushort4 u = ((const ushort4*)h)[i];
        float4 sc = ((const float4*)sc_sh)[cg];
        float4 sh = ((const float4*)sc_sh)[32 + cg];
        float4 v;
        v.x = fmaxf(fmaf(bf2f(u.x), sc.x, sh.x), 0.f);
        v.y = fmaxf(fmaf(bf2f(u.y), sc.y, sh.y), 0.f);
        v.z = fmaxf(fmaf(bf2f(u.z), sc.z, sh.z), 0.f);
        v.w = fmaxf(fmaf(bf2f(u.w), sc.w, sh.w), 0.f);
        ((float4*)out)[i] = v;
    }
}

// ============================================================
// Launch
// ============================================================
extern "C" void kernel_launch(void* const* d_in, const int* in_sizes, int n_in,
                              void* d_out, int out_size, void* d_ws, size_t ws_size,
                              hipStream_t stream) {
    const float* x = (const float*)d_in[0];
    const int* ei = (const int*)d_in[1];
    const int* src = ei;
    const int* dst = ei + N_EDGES;
    const float* Wm[3] = {(const float*)d_in[2], (const float*)d_in[6], (const float*)d_in[10]};
    const float* gm[3] = {(const float*)d_in[4], (const float*)d_in[8], (const float*)d_in[12]};
    const float* bm[3] = {(const float*)d_in[5], (const float*)d_in[9], (const float*)d_in[13]};

    char* p = (char*)d_ws;
    auto carve = [&](size_t bytes) { char* r = p; p += (bytes + 255) & ~(size_t)255; return r; };
    unsigned short* hwB    = (unsigned short*)carve((size_t)N_NODES * D * sizeof(unsigned short));
    unsigned short* aggbf  = (unsigned short*)carve((size_t)N_NODES * D * sizeof(unsigned short));
    unsigned short* Wt     = (unsigned short*)carve((size_t)3 * D * D * sizeof(unsigned short));
    float*          dinv   = (float*)carve((N_NODES + 64) * sizeof(float));
    unsigned int*   cnt8   = (unsigned int*)carve((size_t)(N_NODES * 8 + NREP * 256) * sizeof(unsigned int));
    float*          rep    = (float*)(cnt8 + (size_t)N_NODES * 8);
    unsigned short* csr    = (unsigned short*)carve((size_t)N_NODES * ROWL * sizeof(unsigned short));
    float*          sc_sh  = (float*)carve(256 * sizeof(float));

    // ---- prep: zero counters+BN replicas, transpose weights ----
    hipMemsetAsync(cnt8, 0, (size_t)(N_NODES * 8 + NREP * 256) * sizeof(unsigned int), stream);
    prep_weights_kernel<<<3, 256, 0, stream>>>(Wm[0], Wm[1], Wm[2], Wt);

    // ---- fused: CSR fill || layer-0 GEMM (independent) ----
    fused_fill_gemm0_kernel<<<FILL_BLOCKS + GEMM_BLOCKS, 256, 0, stream>>>(
        src, dst, cnt8, csr, x, Wt, hwB);
    compute_dinv_kernel<<<(N_NODES + 255) / 256, 256, 0, stream>>>(cnt8, dinv);

    // ---- layer 0: weighted gather (hw unscaled) ----
    gather_agg_stats_kernel<<<N_NODES / 8, 256, 0, stream>>>(hwB, csr, cnt8, dinv, aggbf, rep, 1);
    bn_reduce_finalize_kernel<<<1, 128, 0, stream>>>(gm[0], bm[0], rep, sc_sh);

    // ---- layers 1,2: BN fused into GEMM, dinv pre-scaled hw ----
    for (int l = 1; l < 3; l++) {
        gemm_mfma_kernel<<<GEMM_BLOCKS, 256, 0, stream>>>(aggbf, Wt + (size_t)l * D * D, sc_sh, dinv, hwB);
        gather_agg_stats_kernel<<<N_NODES / 8, 256, 0, stream>>>(hwB, csr, cnt8, dinv, aggbf, rep, 0);
        bn_reduce_finalize_kernel<<<1, 128, 0, stream>>>(gm[l], bm[l], rep, sc_sh);
    }
    bn_apply_kernel<<<2048, 256, 0, stream>>>(aggbf, sc_sh, (float*)d_out);
}

// Round 10
// 488.363 us; speedup vs baseline: 1.5471x; 1.2013x over previous
//
#include <hip/hip_runtime.h>
#include <math.h>

#define N_NODES 50000
#define N_EDGES 1600000
#define D 128
#define BN_EPS 1e-5f

#define NSLICE 8
#define SLICE_NODES 6250        // divides 50000 exactly
#define SUBB 24                 // slots per (node, src-slice); Poisson(4), P(>=24)~8e-12
#define ROWL (NSLICE * SUBB)    // 192 u16 per node = 384 B
#define NREP 64                 // BN partial-sum replicas
#define FILL_BLOCKS 2048        // 256 teams/slice
#define GEMM_BLOCKS ((N_NODES + 63) / 64)   // 782

typedef __attribute__((ext_vector_type(8))) short short8;
typedef __attribute__((ext_vector_type(8))) unsigned short ushort8v;
typedef __attribute__((ext_vector_type(4))) float f32x4;

// bf16 helpers (manual, RNE)
__device__ __forceinline__ unsigned short f2bf(float f) {
    unsigned u = __float_as_uint(f);
    u += 0x7FFFu + ((u >> 16) & 1u);
    return (unsigned short)(u >> 16);
}
__device__ __forceinline__ float bf2f(unsigned short u) {
    return __uint_as_float(((unsigned)u) << 16);
}

// ============================================================
// Fill body: sub-bucketed u16 CSR, ONE edge pass, XCD-sliced by dst
// (write window 2.4 MB/slice fits private L2). csr[d][t][pos], t=src-slice.
// ============================================================
__device__ __forceinline__ void fill_body(int blk, const int* __restrict__ src,
                                          const int* __restrict__ dst,
                                          unsigned int* __restrict__ cnt8,
                                          unsigned short* __restrict__ csr) {
    int slice = blk & (NSLICE - 1);
    int b = blk >> 3;
    const int nb = FILL_BLOCKS >> 3;
    int lo = slice * SLICE_NODES, hi = lo + SLICE_NODES;
    for (int e = b * 256 + threadIdx.x; e < N_EDGES; e += nb * 256) {
        int d = dst[e];
        if (d >= lo && d < hi) {
            int s = src[e];
            int t = s / SLICE_NODES;
            unsigned pos = atomicAdd(&cnt8[(d << 3) + t], 1u);
            if (pos < SUBB) csr[(size_t)d * ROWL + t * SUBB + pos] = (unsigned short)s;
        }
    }
}

// ============================================================
// GEMM body: outbf[64 rows](bf16) = act(A) @ W  [+ optional dinv row-scale]
//   apply_bn=0: A = Af32 (fp32 -> bf16), act = identity
//   apply_bn=1: A = Abf (bf16), act = relu(a*sc+sh)
// 4 waves x 16 rows; global-direct fragments (m89-verified layouts).
// ============================================================
__device__ __forceinline__ void gemm_body(int bid, const float* __restrict__ Af32,
                                          const unsigned short* __restrict__ Abf,
                                          const unsigned short* __restrict__ Wt,
                                          const float* __restrict__ sc_sh,
                                          const float* __restrict__ dinv,
                                          int apply_bn,
                                          unsigned short* __restrict__ outbf,
                                          unsigned short* Cs) {   // [4][16][136]
    int tid = threadIdx.x;
    int w = tid >> 6;
    int lane = tid & 63;
    int r = lane & 15, quad = lane >> 4;
    int rowbase = bid * 64 + w * 16;
    int arow = rowbase + r;
    int arowc = (arow < N_NODES) ? arow : 0;

    f32x4 acc[8] = {};
#pragma unroll
    for (int kc = 0; kc < 128; kc += 32) {
        int ko = kc + quad * 8;
        short8 a;
        if (apply_bn) {
            short8 araw = *(const short8*)&Abf[(size_t)arowc * D + ko];
            const float* sc = &sc_sh[ko];
            const float* sh = &sc_sh[128 + ko];
#pragma unroll
            for (int j = 0; j < 8; j++) {
                float v = bf2f((unsigned short)araw[j]);
                v = fmaxf(fmaf(v, sc[j], sh[j]), 0.f);
                a[j] = (short)f2bf(v);
            }
        } else {
            float4 v0 = *(const float4*)&Af32[(size_t)arowc * D + ko];
            float4 v1 = *(const float4*)&Af32[(size_t)arowc * D + ko + 4];
            a[0] = (short)f2bf(v0.x); a[1] = (short)f2bf(v0.y);
            a[2] = (short)f2bf(v0.z); a[3] = (short)f2bf(v0.w);
            a[4] = (short)f2bf(v1.x); a[5] = (short)f2bf(v1.y);
            a[6] = (short)f2bf(v1.z); a[7] = (short)f2bf(v1.w);
        }
#pragma unroll
        for (int ct = 0; ct < 8; ct++) {
            short8 b = *(const short8*)&Wt[(size_t)(ct * 16 + r) * D + ko];
            acc[ct] = __builtin_amdgcn_mfma_f32_16x16x32_bf16(a, b, acc[ct], 0, 0, 0);
        }
    }
    float dv[4] = {1.f, 1.f, 1.f, 1.f};
    if (dinv) {
        float4 d4 = *(const float4*)&dinv[rowbase + quad * 4];  // padded past N
        dv[0] = d4.x; dv[1] = d4.y; dv[2] = d4.z; dv[3] = d4.w;
    }
    // epilogue: wave-private LDS staging (no cross-wave deps -> no barrier)
#pragma unroll
    for (int ct = 0; ct < 8; ct++)
#pragma unroll
        for (int i = 0; i < 4; i++)
            Cs[w * 2176 + (quad * 4 + i) * 136 + ct * 16 + r] = f2bf(acc[ct][i] * dv[i]);

    int r2 = lane >> 2;   // 0..15
    int seg = lane & 3;   // 0..3, 32 cols each
    int orow = rowbase + r2;
    if (orow < N_NODES) {
#pragma unroll
        for (int jj = 0; jj < 4; jj++) {
            *(ushort8v*)&outbf[(size_t)orow * D + seg * 32 + jj * 8] =
                *(const ushort8v*)&Cs[w * 2176 + r2 * 136 + seg * 32 + jj * 8];
        }
    }
}

// ============================================================
// Fused: CSR fill (blocks [0,2048)) || layer-0 GEMM (raw, no dinv/BN).
// Independent work; fusion hides gemm0 (~45us) inside fill (~105us).
// ============================================================
__global__ __launch_bounds__(256) void fused_fill_gemm0_kernel(const int* __restrict__ src,
                                                               const int* __restrict__ dst,
                                                               unsigned int* __restrict__ cnt8,
                                                               unsigned short* __restrict__ csr,
                                                               const float* __restrict__ x,
                                                               const unsigned short* __restrict__ Wt0,
                                                               unsigned short* __restrict__ hwB) {
    __shared__ unsigned short Cs[4 * 16 * 136];
    if (blockIdx.x < FILL_BLOCKS) {
        fill_body(blockIdx.x, src, dst, cnt8, csr);
    } else {
        gemm_body(blockIdx.x - FILL_BLOCKS, x, nullptr, Wt0, nullptr, nullptr, 0, hwB, Cs);
    }
}

// standalone GEMM for layers 1,2 (BN fused, dinv pre-scale)
__global__ __launch_bounds__(256) void gemm_mfma_kernel(const unsigned short* __restrict__ Abf,
                                                        const unsigned short* __restrict__ Wt,
                                                        const float* __restrict__ sc_sh,
                                                        const float* __restrict__ dinv,
                                                        unsigned short* __restrict__ outbf) {
    __shared__ unsigned short Cs[4 * 16 * 136];
    gemm_body(blockIdx.x, nullptr, Abf, Wt, sc_sh, dinv, 1, outbf, Cs);
}

__global__ void compute_dinv_kernel(const unsigned int* __restrict__ cnt8, float* __restrict__ dinv) {
    int n = blockIdx.x * blockDim.x + threadIdx.x;
    if (n < N_NODES) {
        const uint4* c = (const uint4*)&cnt8[n << 3];
        uint4 a = c[0], b = c[1];
        unsigned deg = a.x + a.y + a.z + a.w + b.x + b.y + b.z + b.w;
        dinv[n] = rsqrtf((float)deg + 2.0f);   // improved=True: self-loop weight 2
    }
}

// ============================================================
// Per-layer weight prep: Wt[n][k] = bf16(W[k][n]), 3 layers, 3 blocks.
// ============================================================
__global__ void prep_weights_kernel(const float* __restrict__ W0, const float* __restrict__ W1,
                                    const float* __restrict__ W2, unsigned short* __restrict__ Wt) {
    const float* W = (blockIdx.x == 0) ? W0 : (blockIdx.x == 1) ? W1 : W2;
    unsigned short* o = Wt + (size_t)blockIdx.x * D * D;
    int t = threadIdx.x;
    int n = t & 127, half = t >> 7;
    __attribute__((aligned(16))) unsigned short buf[64];
    for (int j = 0; j < 64; j++) {
        int k = half * 64 + j;
        buf[j] = f2bf(W[(size_t)k * D + n]);
    }
    for (int j = 0; j < 64; j += 8)
        *(ushort8v*)&o[(size_t)n * D + half * 64 + j] = *(const ushort8v*)&buf[j];
}

// ============================================================
// Fused gather + BN-stats — 4 nodes/wave in 16-lane groups, lane owns
// 8 cols (ushort8 = 16B loads; 16 lanes x 16B = one full 256B row per
// group, 1KB per wave load instr). 4 independent load chains per wave
// (vs r6's 2) at only ~30 VGPR — attacks the latency bound without
// r8's occupancy collapse. SUBB=24 > 16 -> two index rounds.
//   weighted=1 (layer 0, hw raw):   agg = di*( sum dinv[s]*hw[s] + 2*di*hw[g] )
//   weighted=0 (layers 1+, hw pre-scaled): agg = di*( sum hw'[s] + 2*hw'[g] )
// Sub-buckets swept slice 0..7 in phase -> small concurrent hw window.
// ============================================================
__global__ __launch_bounds__(256) void gather_agg_stats_kernel(const unsigned short* __restrict__ hw,
                                                               const unsigned short* __restrict__ csr,
                                                               const unsigned int* __restrict__ cnt8,
                                                               const float* __restrict__ dinv,
                                                               unsigned short* __restrict__ out,
                                                               float* __restrict__ rep,
                                                               int weighted) {
    __shared__ float part[16][256];
    int g16 = threadIdx.x >> 4, lane = threadIdx.x & 15;
    int g = blockIdx.x * 16 + g16;             // 3125 * 16 = 50000 exact
    const ushort8v* hwv = (const ushort8v*)hw; // row = 16 x ushort8
    float di = dinv[g];
    ushort8v sv = hwv[(size_t)g * 16 + lane];
    float w0 = weighted ? (2.f * di) : 2.f;
    float acc[8];
#pragma unroll
    for (int k = 0; k < 8; k++) acc[k] = w0 * bf2f((unsigned short)sv[k]);
    const unsigned short* row = csr + (size_t)g * ROWL;
#pragma unroll 1
    for (int t = 0; t < NSLICE; t++) {
        int dt = (int)cnt8[(g << 3) + t];
        if (dt > SUBB) dt = SUBB;
        int sA = 0, sB = 0; float wA = 0.f, wB = 0.f;
        if (lane < dt) {
            sA = (int)row[t * SUBB + lane];
            if (weighted) wA = dinv[sA];
        }
        if (lane + 16 < dt) {
            sB = (int)row[t * SUBB + 16 + lane];
            if (weighted) wB = dinv[sB];
        }
        int d1 = dt < 16 ? dt : 16;
        if (weighted) {
            for (int j = 0; j < d1; j++) {
                int sj = __shfl(sA, j, 16);
                float wj = __shfl(wA, j, 16);
                ushort8v v = hwv[(size_t)sj * 16 + lane];
#pragma unroll
                for (int k = 0; k < 8; k++) acc[k] = fmaf(wj, bf2f((unsigned short)v[k]), acc[k]);
            }
            for (int j = 0; j < dt - 16; j++) {
                int sj = __shfl(sB, j, 16);
                float wj = __shfl(wB, j, 16);
                ushort8v v = hwv[(size_t)sj * 16 + lane];
#pragma unroll
                for (int k = 0; k < 8; k++) acc[k] = fmaf(wj, bf2f((unsigned short)v[k]), acc[k]);
            }
        } else {
            for (int j = 0; j < d1; j++) {
                int sj = __shfl(sA, j, 16);
                ushort8v v = hwv[(size_t)sj * 16 + lane];
#pragma unroll
                for (int k = 0; k < 8; k++) acc[k] += bf2f((unsigned short)v[k]);
            }
            for (int j = 0; j < dt - 16; j++) {
                int sj = __shfl(sB, j, 16);
                ushort8v v = hwv[(size_t)sj * 16 + lane];
#pragma unroll
                for (int k = 0; k < 8; k++) acc[k] += bf2f((unsigned short)v[k]);
            }
        }
    }
    ushort8v o;
#pragma unroll
    for (int k = 0; k < 8; k++) { acc[k] *= di; o[k] = f2bf(acc[k]); }
    ((ushort8v*)out)[(size_t)g * 16 + lane] = o;

    // BN partials: cols c = lane*8+k; sums at [g16][c], sumsq at [g16][128+c]
    float4 s0 = make_float4(acc[0], acc[1], acc[2], acc[3]);
    float4 s1 = make_float4(acc[4], acc[5], acc[6], acc[7]);
    *(float4*)&part[g16][lane * 8]     = s0;
    *(float4*)&part[g16][lane * 8 + 4] = s1;
    *(float4*)&part[g16][128 + lane * 8] =
        make_float4(s0.x * s0.x, s0.y * s0.y, s0.z * s0.z, s0.w * s0.w);
    *(float4*)&part[g16][128 + lane * 8 + 4] =
        make_float4(s1.x * s1.x, s1.y * s1.y, s1.z * s1.z, s1.w * s1.w);
    __syncthreads();
    int c = threadIdx.x;   // 0..255: 0..127 sums, 128..255 sumsq
    float tot = 0.f;
#pragma unroll
    for (int g2 = 0; g2 < 16; g2++) tot += part[g2][c];
    atomicAdd(&rep[(blockIdx.x & (NREP - 1)) * 256 + c], tot);
}

// ============================================================
// Reduce NREP replicas -> sc/sh; re-zero replicas for next layer.
// ============================================================
__global__ void bn_reduce_finalize_kernel(const float* __restrict__ gamma,
                                          const float* __restrict__ beta,
                                          float* __restrict__ rep,
                                          float* __restrict__ sc_sh) {
    int c = threadIdx.x;
    if (c >= 128) return;
    float s = 0.f, q = 0.f;
#pragma unroll 4
    for (int rr = 0; rr < NREP; rr++) {
        s += rep[rr * 256 + c];
        q += rep[rr * 256 + 128 + c];
        rep[rr * 256 + c] = 0.f;
        rep[rr * 256 + 128 + c] = 0.f;
    }
    float inv_n = 1.0f / (float)N_NODES;
    float mean = s * inv_n;
    float var = q * inv_n - mean * mean;
    float inv = rsqrtf(var + BN_EPS);
    float sc = gamma[c] * inv;
    sc_sh[c] = sc;
    sc_sh[128 + c] = beta[c] - mean * sc;
}

// final layer: bf16 agg -> BN+ReLU -> fp32 d_out
__global__ void bn_apply_kernel(const unsigned short* __restrict__ h,
                                const float* __restrict__ sc_sh,
                                float* __restrict__ out) {
    int i = blockIdx.x * blockDim.x + threadIdx.x;
    int stride = gridDim.x * blockDim.x;
    const int total = N_NODES * 32;
    for (; i < total; i += stride) {
        int cg = i & 31;
        ushort4 u = ((const ushort4*)h)[i];
        float4 sc = ((const float4*)sc_sh)[cg];
        float4 sh = ((const float4*)sc_sh)[32 + cg];
        float4 v;
        v.x = fmaxf(fmaf(bf2f(u.x), sc.x, sh.x), 0.f);
        v.y = fmaxf(fmaf(bf2f(u.y), sc.y, sh.y), 0.f);
        v.z = fmaxf(fmaf(bf2f(u.z), sc.z, sh.z), 0.f);
        v.w = fmaxf(fmaf(bf2f(u.w), sc.w, sh.w), 0.f);
        ((float4*)out)[i] = v;
    }
}

// ============================================================
// Launch
// ============================================================
extern "C" void kernel_launch(void* const* d_in, const int* in_sizes, int n_in,
                              void* d_out, int out_size, void* d_ws, size_t ws_size,
                              hipStream_t stream) {
    const float* x = (const float*)d_in[0];
    const int* ei = (const int*)d_in[1];
    const int* src = ei;
    const int* dst = ei + N_EDGES;
    const float* Wm[3] = {(const float*)d_in[2], (const float*)d_in[6], (const float*)d_in[10]};
    const float* gm[3] = {(const float*)d_in[4], (const float*)d_in[8], (const float*)d_in[12]};
    const float* bm[3] = {(const float*)d_in[5], (const float*)d_in[9], (const float*)d_in[13]};

    char* p = (char*)d_ws;
    auto carve = [&](size_t bytes) { char* r = p; p += (bytes + 255) & ~(size_t)255; return r; };
    unsigned short* hwB    = (unsigned short*)carve((size_t)N_NODES * D * sizeof(unsigned short));
    unsigned short* aggbf  = (unsigned short*)carve((size_t)N_NODES * D * sizeof(unsigned short));
    unsigned short* Wt     = (unsigned short*)carve((size_t)3 * D * D * sizeof(unsigned short));
    float*          dinv   = (float*)carve((N_NODES + 64) * sizeof(float));
    unsigned int*   cnt8   = (unsigned int*)carve((size_t)(N_NODES * 8 + NREP * 256) * sizeof(unsigned int));
    float*          rep    = (float*)(cnt8 + (size_t)N_NODES * 8);
    unsigned short* csr    = (unsigned short*)carve((size_t)N_NODES * ROWL * sizeof(unsigned short));
    float*          sc_sh  = (float*)carve(256 * sizeof(float));

    // ---- prep: zero counters+BN replicas, transpose weights ----
    hipMemsetAsync(cnt8, 0, (size_t)(N_NODES * 8 + NREP * 256) * sizeof(unsigned int), stream);
    prep_weights_kernel<<<3, 256, 0, stream>>>(Wm[0], Wm[1], Wm[2], Wt);

    // ---- fused: CSR fill || layer-0 GEMM (independent) ----
    fused_fill_gemm0_kernel<<<FILL_BLOCKS + GEMM_BLOCKS, 256, 0, stream>>>(
        src, dst, cnt8, csr, x, Wt, hwB);
    compute_dinv_kernel<<<(N_NODES + 255) / 256, 256, 0, stream>>>(cnt8, dinv);

    // ---- layer 0: weighted gather (hw unscaled) ----
    gather_agg_stats_kernel<<<N_NODES / 16, 256, 0, stream>>>(hwB, csr, cnt8, dinv, aggbf, rep, 1);
    bn_reduce_finalize_kernel<<<1, 128, 0, stream>>>(gm[0], bm[0], rep, sc_sh);

    // ---- layers 1,2: BN fused into GEMM, dinv pre-scaled hw ----
    for (int l = 1; l < 3; l++) {
        gemm_mfma_kernel<<<GEMM_BLOCKS, 256, 0, stream>>>(aggbf, Wt + (size_t)l * D * D, sc_sh, dinv, hwB);
        gather_agg_stats_kernel<<<N_NODES / 16, 256, 0, stream>>>(hwB, csr, cnt8, dinv, aggbf, rep, 0);
        bn_reduce_finalize_kernel<<<1, 128, 0, stream>>>(gm[l], bm[l], rep, sc_sh);
    }
    bn_apply_kernel<<<2048, 256, 0, stream>>>(aggbf, sc_sh, (float*)d_out);
}

// Round 11
// 481.423 us; speedup vs baseline: 1.5694x; 1.0144x over previous
//
#include <hip/hip_runtime.h>
#include <math.h>

#define N_NODES 50000
#define N_EDGES 1600000
#define D 128
#define BN_EPS 1e-5f

#define NSLICE 8
#define SLICE_NODES 6250        // divides 50000 exactly
#define SUBB 24                 // slots per (node, src-slice); Poisson(4), P(>=24)~8e-12
#define ROWL (NSLICE * SUBB)    // 192 u16 per node = 384 B
#define NREP 64                 // BN partial-sum replicas
#define FILL_BLOCKS 2048        // 256 teams/slice
#define GEMM0_BLOCKS ((N_NODES + 63) / 64)   // 782 (64 rows, 4 waves) — fused with fill
#define GEMM_BLOCKS ((N_NODES + 31) / 32)    // 1563 (32 rows, 2 waves) — better tail balance

typedef __attribute__((ext_vector_type(8))) short short8;
typedef __attribute__((ext_vector_type(8))) unsigned short ushort8v;
typedef __attribute__((ext_vector_type(4))) float f32x4;

// bf16 helpers (manual, RNE)
__device__ __forceinline__ unsigned short f2bf(float f) {
    unsigned u = __float_as_uint(f);
    u += 0x7FFFu + ((u >> 16) & 1u);
    return (unsigned short)(u >> 16);
}
__device__ __forceinline__ float bf2f(unsigned short u) {
    return __uint_as_float(((unsigned)u) << 16);
}

// ============================================================
// Fill: sub-bucketed u16 CSR, ONE edge pass, XCD-sliced by dst.
// 4-way batched grid-stride: 4 independent dst-load + match chains in
// flight per outer iteration (the fill is latency-bound: VALUBusy 6%,
// serial per-iteration load->atomic->store chains were the wall).
// ============================================================
__device__ __forceinline__ void fill_edge(int d, int e, int lo, int hi,
                                          const int* __restrict__ src,
                                          unsigned int* __restrict__ cnt8,
                                          unsigned short* __restrict__ csr) {
    if (d >= lo && d < hi) {
        int s = src[e];
        int t = s / SLICE_NODES;
        unsigned pos = atomicAdd(&cnt8[(d << 3) + t], 1u);
        if (pos < SUBB) csr[(size_t)d * ROWL + t * SUBB + pos] = (unsigned short)s;
    }
}

__device__ __forceinline__ void fill_body(int blk, const int* __restrict__ src,
                                          const int* __restrict__ dst,
                                          unsigned int* __restrict__ cnt8,
                                          unsigned short* __restrict__ csr) {
    int slice = blk & (NSLICE - 1);
    int b = blk >> 3;
    const int stride = (FILL_BLOCKS >> 3) * 256;
    int lo = slice * SLICE_NODES, hi = lo + SLICE_NODES;
    int e = b * 256 + threadIdx.x;
    for (; e + 3 * stride < N_EDGES; e += 4 * stride) {
        int d0 = dst[e];
        int d1 = dst[e + stride];
        int d2 = dst[e + 2 * stride];
        int d3 = dst[e + 3 * stride];
        fill_edge(d0, e, lo, hi, src, cnt8, csr);
        fill_edge(d1, e + stride, lo, hi, src, cnt8, csr);
        fill_edge(d2, e + 2 * stride, lo, hi, src, cnt8, csr);
        fill_edge(d3, e + 3 * stride, lo, hi, src, cnt8, csr);
    }
    for (; e < N_EDGES; e += stride)
        fill_edge(dst[e], e, lo, hi, src, cnt8, csr);
}

// ============================================================
// GEMM body (16 rows per wave): out[rowbase..rowbase+15] = act(A) @ W
//   apply_bn=0: A = Af32 (fp32 -> bf16), act = identity
//   apply_bn=1: A = Abf (bf16), act = relu(a*sc+sh)
// Global-direct fragments (m89-verified layouts); optional dinv row-scale.
// ============================================================
__device__ __forceinline__ void gemm_body(int rowbase, const float* __restrict__ Af32,
                                          const unsigned short* __restrict__ Abf,
                                          const unsigned short* __restrict__ Wt,
                                          const float* __restrict__ sc_sh,
                                          const float* __restrict__ dinv,
                                          int apply_bn,
                                          unsigned short* __restrict__ outbf,
                                          unsigned short* Cs) {   // per-wave 16x136 at Cs[w*2176]
    int tid = threadIdx.x;
    int w = tid >> 6;
    int lane = tid & 63;
    int r = lane & 15, quad = lane >> 4;
    rowbase += w * 16;
    int arow = rowbase + r;
    int arowc = (arow < N_NODES) ? arow : 0;

    f32x4 acc[8] = {};
#pragma unroll
    for (int kc = 0; kc < 128; kc += 32) {
        int ko = kc + quad * 8;
        short8 a;
        if (apply_bn) {
            short8 araw = *(const short8*)&Abf[(size_t)arowc * D + ko];
            const float* sc = &sc_sh[ko];
            const float* sh = &sc_sh[128 + ko];
#pragma unroll
            for (int j = 0; j < 8; j++) {
                float v = bf2f((unsigned short)araw[j]);
                v = fmaxf(fmaf(v, sc[j], sh[j]), 0.f);
                a[j] = (short)f2bf(v);
            }
        } else {
            float4 v0 = *(const float4*)&Af32[(size_t)arowc * D + ko];
            float4 v1 = *(const float4*)&Af32[(size_t)arowc * D + ko + 4];
            a[0] = (short)f2bf(v0.x); a[1] = (short)f2bf(v0.y);
            a[2] = (short)f2bf(v0.z); a[3] = (short)f2bf(v0.w);
            a[4] = (short)f2bf(v1.x); a[5] = (short)f2bf(v1.y);
            a[6] = (short)f2bf(v1.z); a[7] = (short)f2bf(v1.w);
        }
#pragma unroll
        for (int ct = 0; ct < 8; ct++) {
            short8 b = *(const short8*)&Wt[(size_t)(ct * 16 + r) * D + ko];
            acc[ct] = __builtin_amdgcn_mfma_f32_16x16x32_bf16(a, b, acc[ct], 0, 0, 0);
        }
    }
    float dv[4] = {1.f, 1.f, 1.f, 1.f};
    if (dinv) {
        float4 d4 = *(const float4*)&dinv[rowbase + quad * 4];  // padded past N
        dv[0] = d4.x; dv[1] = d4.y; dv[2] = d4.z; dv[3] = d4.w;
    }
    // epilogue: wave-private LDS staging (no cross-wave deps -> no barrier)
#pragma unroll
    for (int ct = 0; ct < 8; ct++)
#pragma unroll
        for (int i = 0; i < 4; i++)
            Cs[w * 2176 + (quad * 4 + i) * 136 + ct * 16 + r] = f2bf(acc[ct][i] * dv[i]);

    int r2 = lane >> 2;   // 0..15
    int seg = lane & 3;   // 0..3, 32 cols each
    int orow = rowbase + r2;
    if (orow < N_NODES) {
#pragma unroll
        for (int jj = 0; jj < 4; jj++) {
            *(ushort8v*)&outbf[(size_t)orow * D + seg * 32 + jj * 8] =
                *(const ushort8v*)&Cs[w * 2176 + r2 * 136 + seg * 32 + jj * 8];
        }
    }
}

// ============================================================
// Fused: CSR fill (blocks [0,2048)) || layer-0 GEMM (raw, no dinv/BN).
// Independent work; fusion hides gemm0 inside fill.
// ============================================================
__global__ __launch_bounds__(256) void fused_fill_gemm0_kernel(const int* __restrict__ src,
                                                               const int* __restrict__ dst,
                                                               unsigned int* __restrict__ cnt8,
                                                               unsigned short* __restrict__ csr,
                                                               const float* __restrict__ x,
                                                               const unsigned short* __restrict__ Wt0,
                                                               unsigned short* __restrict__ hwB) {
    __shared__ unsigned short Cs[4 * 2176];
    if (blockIdx.x < FILL_BLOCKS) {
        fill_body(blockIdx.x, src, dst, cnt8, csr);
    } else {
        gemm_body((blockIdx.x - FILL_BLOCKS) * 64, x, nullptr, Wt0, nullptr, nullptr, 0, hwB, Cs);
    }
}

// standalone GEMM for layers 1,2 (BN fused, dinv pre-scale); 128 thr = 2 waves,
// 32 rows/block -> 1563 blocks (782-block config wasted a 14/256 dispatch tail)
__global__ __launch_bounds__(128) void gemm_mfma_kernel(const unsigned short* __restrict__ Abf,
                                                        const unsigned short* __restrict__ Wt,
                                                        const float* __restrict__ sc_sh,
                                                        const float* __restrict__ dinv,
                                                        unsigned short* __restrict__ outbf) {
    __shared__ unsigned short Cs[2 * 2176];
    gemm_body(blockIdx.x * 32, nullptr, Abf, Wt, sc_sh, dinv, 1, outbf, Cs);
}

__global__ void compute_dinv_kernel(const unsigned int* __restrict__ cnt8, float* __restrict__ dinv) {
    int n = blockIdx.x * blockDim.x + threadIdx.x;
    if (n < N_NODES) {
        const uint4* c = (const uint4*)&cnt8[n << 3];
        uint4 a = c[0], b = c[1];
        unsigned deg = a.x + a.y + a.z + a.w + b.x + b.y + b.z + b.w;
        dinv[n] = rsqrtf((float)deg + 2.0f);   // improved=True: self-loop weight 2
    }
}

// ============================================================
// Per-layer weight prep: Wt[n][k] = bf16(W[k][n]), 3 layers, 3 blocks.
// ============================================================
__global__ void prep_weights_kernel(const float* __restrict__ W0, const float* __restrict__ W1,
                                    const float* __restrict__ W2, unsigned short* __restrict__ Wt) {
    const float* W = (blockIdx.x == 0) ? W0 : (blockIdx.x == 1) ? W1 : W2;
    unsigned short* o = Wt + (size_t)blockIdx.x * D * D;
    int t = threadIdx.x;
    int n = t & 127, half = t >> 7;
    __attribute__((aligned(16))) unsigned short buf[64];
    for (int j = 0; j < 64; j++) {
        int k = half * 64 + j;
        buf[j] = f2bf(W[(size_t)k * D + n]);
    }
    for (int j = 0; j < 64; j += 8)
        *(ushort8v*)&o[(size_t)n * D + half * 64 + j] = *(const ushort8v*)&buf[j];
}

// ============================================================
// Fused gather + BN-stats — 4 nodes/wave in 16-lane groups, lane owns
// 8 cols (ushort8 = 16B): 4 independent load chains/wave at ~30 VGPR
// (r10: 92 -> ~65us). DO NOT re-batch manually (r7/r8 regressions).
//   weighted=1 (layer 0, hw raw):   agg = di*( sum dinv[s]*hw[s] + 2*di*hw[g] )
//   weighted=0 (layers 1+, pre-scaled): agg = di*( sum hw'[s] + 2*hw'[g] )
// ============================================================
__global__ __launch_bounds__(256) void gather_agg_stats_kernel(const unsigned short* __restrict__ hw,
                                                               const unsigned short* __restrict__ csr,
                                                               const unsigned int* __restrict__ cnt8,
                                                               const float* __restrict__ dinv,
                                                               unsigned short* __restrict__ out,
                                                               float* __restrict__ rep,
                                                               int weighted) {
    __shared__ float part[16][256];
    int g16 = threadIdx.x >> 4, lane = threadIdx.x & 15;
    int g = blockIdx.x * 16 + g16;             // 3125 * 16 = 50000 exact
    const ushort8v* hwv = (const ushort8v*)hw; // row = 16 x ushort8
    float di = dinv[g];
    ushort8v sv = hwv[(size_t)g * 16 + lane];
    float w0 = weighted ? (2.f * di) : 2.f;
    float acc[8];
#pragma unroll
    for (int k = 0; k < 8; k++) acc[k] = w0 * bf2f((unsigned short)sv[k]);
    const unsigned short* row = csr + (size_t)g * ROWL;
#pragma unroll 1
    for (int t = 0; t < NSLICE; t++) {
        int dt = (int)cnt8[(g << 3) + t];
        if (dt > SUBB) dt = SUBB;
        int sA = 0, sB = 0; float wA = 0.f, wB = 0.f;
        if (lane < dt) {
            sA = (int)row[t * SUBB + lane];
            if (weighted) wA = dinv[sA];
        }
        if (lane + 16 < dt) {
            sB = (int)row[t * SUBB + 16 + lane];
            if (weighted) wB = dinv[sB];
        }
        int d1 = dt < 16 ? dt : 16;
        if (weighted) {
            for (int j = 0; j < d1; j++) {
                int sj = __shfl(sA, j, 16);
                float wj = __shfl(wA, j, 16);
                ushort8v v = hwv[(size_t)sj * 16 + lane];
#pragma unroll
                for (int k = 0; k < 8; k++) acc[k] = fmaf(wj, bf2f((unsigned short)v[k]), acc[k]);
            }
            for (int j = 0; j < dt - 16; j++) {
                int sj = __shfl(sB, j, 16);
                float wj = __shfl(wB, j, 16);
                ushort8v v = hwv[(size_t)sj * 16 + lane];
#pragma unroll
                for (int k = 0; k < 8; k++) acc[k] = fmaf(wj, bf2f((unsigned short)v[k]), acc[k]);
            }
        } else {
            for (int j = 0; j < d1; j++) {
                int sj = __shfl(sA, j, 16);
                ushort8v v = hwv[(size_t)sj * 16 + lane];
#pragma unroll
                for (int k = 0; k < 8; k++) acc[k] += bf2f((unsigned short)v[k]);
            }
            for (int j = 0; j < dt - 16; j++) {
                int sj = __shfl(sB, j, 16);
                ushort8v v = hwv[(size_t)sj * 16 + lane];
#pragma unroll
                for (int k = 0; k < 8; k++) acc[k] += bf2f((unsigned short)v[k]);
            }
        }
    }
    ushort8v o;
#pragma unroll
    for (int k = 0; k < 8; k++) { acc[k] *= di; o[k] = f2bf(acc[k]); }
    ((ushort8v*)out)[(size_t)g * 16 + lane] = o;

    // BN partials: cols c = lane*8+k; sums at [g16][c], sumsq at [g16][128+c]
    float4 s0 = make_float4(acc[0], acc[1], acc[2], acc[3]);
    float4 s1 = make_float4(acc[4], acc[5], acc[6], acc[7]);
    *(float4*)&part[g16][lane * 8]     = s0;
    *(float4*)&part[g16][lane * 8 + 4] = s1;
    *(float4*)&part[g16][128 + lane * 8] =
        make_float4(s0.x * s0.x, s0.y * s0.y, s0.z * s0.z, s0.w * s0.w);
    *(float4*)&part[g16][128 + lane * 8 + 4] =
        make_float4(s1.x * s1.x, s1.y * s1.y, s1.z * s1.z, s1.w * s1.w);
    __syncthreads();
    int c = threadIdx.x;   // 0..255: 0..127 sums, 128..255 sumsq
    float tot = 0.f;
#pragma unroll
    for (int g2 = 0; g2 < 16; g2++) tot += part[g2][c];
    atomicAdd(&rep[(blockIdx.x & (NREP - 1)) * 256 + c], tot);
}

// ============================================================
// Reduce NREP replicas -> sc/sh; re-zero replicas for next layer.
// ============================================================
__global__ void bn_reduce_finalize_kernel(const float* __restrict__ gamma,
                                          const float* __restrict__ beta,
                                          float* __restrict__ rep,
                                          float* __restrict__ sc_sh) {
    int c = threadIdx.x;
    if (c >= 128) return;
    float s = 0.f, q = 0.f;
#pragma unroll 4
    for (int rr = 0; rr < NREP; rr++) {
        s += rep[rr * 256 + c];
        q += rep[rr * 256 + 128 + c];
        rep[rr * 256 + c] = 0.f;
        rep[rr * 256 + 128 + c] = 0.f;
    }
    float inv_n = 1.0f / (float)N_NODES;
    float mean = s * inv_n;
    float var = q * inv_n - mean * mean;
    float inv = rsqrtf(var + BN_EPS);
    float sc = gamma[c] * inv;
    sc_sh[c] = sc;
    sc_sh[128 + c] = beta[c] - mean * sc;
}

// final layer: bf16 agg -> BN+ReLU -> fp32 d_out
__global__ void bn_apply_kernel(const unsigned short* __restrict__ h,
                                const float* __restrict__ sc_sh,
                                float* __restrict__ out) {
    int i = blockIdx.x * blockDim.x + threadIdx.x;
    int stride = gridDim.x * blockDim.x;
    const int total = N_NODES * 32;
    for (; i < total; i += stride) {
        int cg = i & 31;
        ushort4 u = ((const ushort4*)h)[i];
        float4 sc = ((const float4*)sc_sh)[cg];
        float4 sh = ((const float4*)sc_sh)[32 + cg];
        float4 v;
        v.x = fmaxf(fmaf(bf2f(u.x), sc.x, sh.x), 0.f);
        v.y = fmaxf(fmaf(bf2f(u.y), sc.y, sh.y), 0.f);
        v.z = fmaxf(fmaf(bf2f(u.z), sc.z, sh.z), 0.f);
        v.w = fmaxf(fmaf(bf2f(u.w), sc.w, sh.w), 0.f);
        ((float4*)out)[i] = v;
    }
}

// ============================================================
// Launch
// ============================================================
extern "C" void kernel_launch(void* const* d_in, const int* in_sizes, int n_in,
                              void* d_out, int out_size, void* d_ws, size_t ws_size,
                              hipStream_t stream) {
    const float* x = (const float*)d_in[0];
    const int* ei = (const int*)d_in[1];
    const int* src = ei;
    const int* dst = ei + N_EDGES;
    const float* Wm[3] = {(const float*)d_in[2], (const float*)d_in[6], (const float*)d_in[10]};
    const float* gm[3] = {(const float*)d_in[4], (const float*)d_in[8], (const float*)d_in[12]};
    const float* bm[3] = {(const float*)d_in[5], (const float*)d_in[9], (const float*)d_in[13]};

    char* p = (char*)d_ws;
    auto carve = [&](size_t bytes) { char* r = p; p += (bytes + 255) & ~(size_t)255; return r; };
    unsigned short* hwB    = (unsigned short*)carve((size_t)N_NODES * D * sizeof(unsigned short));
    unsigned short* aggbf  = (unsigned short*)carve((size_t)N_NODES * D * sizeof(unsigned short));
    unsigned short* Wt     = (unsigned short*)carve((size_t)3 * D * D * sizeof(unsigned short));
    float*          dinv   = (float*)carve((N_NODES + 64) * sizeof(float));
    unsigned int*   cnt8   = (unsigned int*)carve((size_t)(N_NODES * 8 + NREP * 256) * sizeof(unsigned int));
    float*          rep    = (float*)(cnt8 + (size_t)N_NODES * 8);
    unsigned short* csr    = (unsigned short*)carve((size_t)N_NODES * ROWL * sizeof(unsigned short));
    float*          sc_sh  = (float*)carve(256 * sizeof(float));

    // ---- prep: zero counters+BN replicas, transpose weights ----
    hipMemsetAsync(cnt8, 0, (size_t)(N_NODES * 8 + NREP * 256) * sizeof(unsigned int), stream);
    prep_weights_kernel<<<3, 256, 0, stream>>>(Wm[0], Wm[1], Wm[2], Wt);

    // ---- fused: CSR fill || layer-0 GEMM (independent) ----
    fused_fill_gemm0_kernel<<<FILL_BLOCKS + GEMM0_BLOCKS, 256, 0, stream>>>(
        src, dst, cnt8, csr, x, Wt, hwB);
    compute_dinv_kernel<<<(N_NODES + 255) / 256, 256, 0, stream>>>(cnt8, dinv);

    // ---- layer 0: weighted gather (hw unscaled) ----
    gather_agg_stats_kernel<<<N_NODES / 16, 256, 0, stream>>>(hwB, csr, cnt8, dinv, aggbf, rep, 1);
    bn_reduce_finalize_kernel<<<1, 128, 0, stream>>>(gm[0], bm[0], rep, sc_sh);

    // ---- layers 1,2: BN fused into GEMM, dinv pre-scaled hw ----
    for (int l = 1; l < 3; l++) {
        gemm_mfma_kernel<<<GEMM_BLOCKS, 128, 0, stream>>>(aggbf, Wt + (size_t)l * D * D, sc_sh, dinv, hwB);
        gather_agg_stats_kernel<<<N_NODES / 16, 256, 0, stream>>>(hwB, csr, cnt8, dinv, aggbf, rep, 0);
        bn_reduce_finalize_kernel<<<1, 128, 0, stream>>>(gm[l], bm[l], rep, sc_sh);
    }
    bn_apply_kernel<<<2048, 256, 0, stream>>>(aggbf, sc_sh, (float*)d_out);
}